// Round 6
// baseline (188.905 us; speedup 1.0000x reference)
//
#include <hip/hip_runtime.h>

#define COUT 64
#define KNB 27
#define BN_EPS 1e-5f
#define NBANDS 6

typedef __attribute__((ext_vector_type(8))) short short8v;  // 8 bf16 (4 VGPRs)
typedef __attribute__((ext_vector_type(4))) float f32x4;

union U4S8 { uint4 u; short8v s; };

// f32 -> bf16, round-to-nearest-even
static __device__ __forceinline__ unsigned f2bf(float f) {
    unsigned u = __float_as_uint(f);
    return (u + 0x7fffu + ((u >> 16) & 1u)) >> 16;
}

// ---------------- Kernel 0: pre-convert x rows to packed bf16 ----------------
__global__ __launch_bounds__(256) void xconv_kernel(
    const float4* __restrict__ x, uint2* __restrict__ xb, int n_in)
{
    int i = blockIdx.x * 256 + threadIdx.x;
    if (i >= n_in) return;
    float4 r = x[i];
    uint2 o;
    o.x = f2bf(r.x) | (f2bf(r.y) << 16);
    o.y = f2bf(r.z) | (f2bf(r.w) << 16);
    xb[i] = o;
}

// ---------------- Kernel 1: banded MFMA gather-conv + BN stats ----------------
// Wave owns 16 nodes. vs R5: the per-band vmcnt(0) DRAIN is removed — bands
// are paced by ISSUE order only (s_barrier + sched_barrier pinning). L2
// locality comes from requests to the same 2MB band being issued in the same
// time window; loads stay in flight across bands, so each wave ends the sweep
// with all 8 gathers outstanding (R4-level MLP) while keeping R5's traffic.
// Correctness never depends on the barriers (per-wave private data).
__global__ __launch_bounds__(256, 8) void conv_stats_kernel(
    const uint2* __restrict__ xb,      // [N_in] packed bf16 rows (8B)
    const float* __restrict__ w,       // [27][4][64]
    const int*   __restrict__ nidx,    // [N_out][27]
    unsigned short* __restrict__ yb,   // [N_out][64] bf16 (workspace)
    float*       __restrict__ stats,   // [128]: sum[64], sumsq[64]
    int n_out, int band)
{
    const int lane = threadIdx.x & 63;
    const int wid  = threadIdx.x >> 6;
    const int row  = lane & 15;   // A-row (node) / B-col (channel) selector
    const int grp  = lane >> 4;   // k-chunk selector
    const int gwave   = blockIdx.x * 4 + wid;
    const int nwaves  = gridDim.x * 4;
    const int ngroups = (n_out + 15) >> 4;
    const int niter   = (ngroups + nwaves - 1) / nwaves;  // uniform trip count

    // ---- stage B fragments into LDS (16 frag-sets x 64 lanes x 16B = 16KB) ----
    __shared__ uint4 blds[16 * 64];
#pragma unroll
    for (int pp = 0; pp < 4; ++pp) {
        const int pair = wid * 4 + pp;        // pair = kb*4 + t
        const int kb = pair >> 2, t = pair & 3;
        const int o = t * 16 + row;
        unsigned e[8];
#pragma unroll
        for (int j = 0; j < 8; ++j) {
            const int k = kb * 32 + grp * 8 + j;
            float v = (k < KNB * 4) ? w[k * COUT + o] : 0.0f;
            e[j] = f2bf(v);
        }
        uint4 f;
        f.x = e[0] | (e[1] << 16);
        f.y = e[2] | (e[3] << 16);
        f.z = e[4] | (e[5] << 16);
        f.w = e[6] | (e[7] << 16);
        blds[pair * 64 + lane] = f;
    }
    __syncthreads();

    float sum[4]   = {0.f, 0.f, 0.f, 0.f};
    float sumsq[4] = {0.f, 0.f, 0.f, 0.f};

    auto load_ia = [&](int gg, int (&ia)[4][2]) {
        const int nodeg = (gg << 4) + row;
        const bool vn = (gg < ngroups) && (nodeg < n_out);
#pragma unroll
        for (int kb = 0; kb < 4; ++kb)
#pragma unroll
            for (int h = 0; h < 2; ++h) {
                const int nb = kb * 8 + grp * 2 + h;
                ia[kb][h] = (vn && nb < KNB) ? nidx[nodeg * KNB + nb] : -1;
            }
    };

    int ia_cur[4][2];
    load_ia(gwave, ia_cur);

    for (int it = 0; it < niter; ++it) {
        const int g = gwave + it * nwaves;   // may exceed ngroups (then ia=-1)

        uint2 xa[4][2];
#pragma unroll
        for (int kb = 0; kb < 4; ++kb)
#pragma unroll
            for (int h = 0; h < 2; ++h) xa[kb][h] = make_uint2(0u, 0u);

        int ia_nxt[4][2];

        // ---- banded gather sweep: issue-order pacing only, NO drains ----
#pragma unroll
        for (int b = 0; b < NBANDS; ++b) {
            const int lo = b * band;
#pragma unroll
            for (int kb = 0; kb < 4; ++kb)
#pragma unroll
                for (int h = 0; h < 2; ++h) {
                    if ((unsigned)(ia_cur[kb][h] - lo) < (unsigned)band)
                        xa[kb][h] = xb[ia_cur[kb][h]];   // exec-masked gather
                }
            if (b == 0) load_ia(g + nwaves, ia_nxt);  // prefetch during band 0
            // pin issue order (compiler must not hoist loads across), then
            // align the block's waves; loads remain in flight.
            __builtin_amdgcn_sched_barrier(0);
            __builtin_amdgcn_s_barrier();
            __builtin_amdgcn_sched_barrier(0);
        }

        // ---- 16 MFMAs; A-frag = raw packed bits, B-frag from LDS ----
        // (compiler inserts the single vmcnt wait before first xa use)
        f32x4 acc[4];
#pragma unroll
        for (int t = 0; t < 4; ++t) acc[t] = (f32x4){0.f, 0.f, 0.f, 0.f};
#pragma unroll
        for (int kb = 0; kb < 4; ++kb) {
            U4S8 a;
            a.u = make_uint4(xa[kb][0].x, xa[kb][0].y, xa[kb][1].x, xa[kb][1].y);
#pragma unroll
            for (int t = 0; t < 4; ++t) {
                U4S8 b;
                b.u = blds[(kb * 4 + t) * 64 + lane];
                acc[t] = __builtin_amdgcn_mfma_f32_16x16x32_bf16(
                             a.s, b.s, acc[t], 0, 0, 0);
            }
        }

        // ---- store y (bf16) + accumulate stats ----
        // C/D layout: channel = t*16 + (lane&15), node = gbase + grp*4 + j.
        const int gbase = g << 4;
#pragma unroll
        for (int t = 0; t < 4; ++t) {
#pragma unroll
            for (int j = 0; j < 4; ++j) {
                const int nr = gbase + grp * 4 + j;
                const float v = acc[t][j];
                if (nr < n_out)
                    yb[(size_t)nr * COUT + t * 16 + row] = (unsigned short)f2bf(v);
                sum[t]   += v;                 // padded rows contribute exact 0
                sumsq[t]  = fmaf(v, v, sumsq[t]);
            }
        }

#pragma unroll
        for (int kb = 0; kb < 4; ++kb)
#pragma unroll
            for (int h = 0; h < 2; ++h) ia_cur[kb][h] = ia_nxt[kb][h];
    }

    // Reduce stats: shfl over grp (16,32), 4-wave LDS reduce, 1 atomic/channel.
    __shared__ float redS[4][4][16];
    __shared__ float redQ[4][4][16];
#pragma unroll
    for (int t = 0; t < 4; ++t) {
        float s = sum[t], q = sumsq[t];
        s += __shfl_xor(s, 16); s += __shfl_xor(s, 32);
        q += __shfl_xor(q, 16); q += __shfl_xor(q, 32);
        if (lane < 16) { redS[wid][t][lane] = s; redQ[wid][t][lane] = q; }
    }
    __syncthreads();
    if (threadIdx.x < 128) {
        const int which = threadIdx.x >> 6;       // 0 = sum, 1 = sumsq
        const int o = threadIdx.x & 63;
        const int t = o >> 4, c = o & 15;
        float tot;
        if (which == 0)
            tot = redS[0][t][c] + redS[1][t][c] + redS[2][t][c] + redS[3][t][c];
        else
            tot = redQ[0][t][c] + redQ[1][t][c] + redQ[2][t][c] + redQ[3][t][c];
        atomicAdd(&stats[which * COUT + o], tot);
    }
}

// ---------------- Kernel 2: finalize BN affine + write depth output ----------------
__global__ void finalize_kernel(
    const float* __restrict__ stats,
    const float* __restrict__ gamma,
    const float* __restrict__ beta,
    float*       __restrict__ scaleshift,  // [128]: scale[64], shift[64]
    const int*   __restrict__ depth,
    float*       __restrict__ out_tail,    // &out[n_pool*64]
    int n_out, int write_depth)
{
    int o = threadIdx.x;
    if (o < COUT) {
        float invn  = 1.0f / (float)n_out;
        float mean  = stats[o] * invn;
        float var   = stats[COUT + o] * invn - mean * mean;  // population var
        float scale = gamma[o] * rsqrtf(var + BN_EPS);
        scaleshift[o]        = scale;
        scaleshift[COUT + o] = beta[o] - mean * scale;
    }
    if (o == 0 && write_depth) {
        out_tail[0] = (float)(depth[0] - 2);
    }
}

// ---------------- Kernel 3: affine + ReLU + max-pool over 8 children ----------------
__global__ __launch_bounds__(256) void pool_kernel(
    const uint2*  __restrict__ yb2,        // y as [N_out][16] packed bf16 quads
    const int*    __restrict__ pidx,       // [N_pool][8]
    const float4* __restrict__ scaleshift4,// [32]: scale4[16], shift4[16]
    float4*       __restrict__ out4,       // [N_pool][16]
    int n_pool)
{
    const int t = blockIdx.x * 256 + threadIdx.x;
    const int q = t & 15;
    const int n = t >> 4;
    if (n >= n_pool) return;

    const float4 sc = scaleshift4[q];
    const float4 sh = scaleshift4[16 + q];

    int idx[8];
#pragma unroll
    for (int j = 0; j < 8; ++j) idx[j] = pidx[n * 8 + j];

    uint2 v[8];
#pragma unroll
    for (int j = 0; j < 8; ++j) v[j] = yb2[(size_t)idx[j] * 16 + q];

    float4 m = make_float4(-INFINITY, -INFINITY, -INFINITY, -INFINITY);
#pragma unroll
    for (int j = 0; j < 8; ++j) {
        float f0 = __uint_as_float(v[j].x << 16);
        float f1 = __uint_as_float(v[j].x & 0xffff0000u);
        float f2 = __uint_as_float(v[j].y << 16);
        float f3 = __uint_as_float(v[j].y & 0xffff0000u);
        m.x = fmaxf(m.x, fmaf(f0, sc.x, sh.x));
        m.y = fmaxf(m.y, fmaf(f1, sc.y, sh.y));
        m.z = fmaxf(m.z, fmaf(f2, sc.z, sh.z));
        m.w = fmaxf(m.w, fmaf(f3, sc.w, sh.w));
    }
    m.x = fmaxf(m.x, 0.f); m.y = fmaxf(m.y, 0.f);
    m.z = fmaxf(m.z, 0.f); m.w = fmaxf(m.w, 0.f);
    out4[(size_t)n * 16 + q] = m;
}

// ---------------- Launch ----------------
extern "C" void kernel_launch(void* const* d_in, const int* in_sizes, int n_in_args,
                              void* d_out, int out_size, void* d_ws, size_t ws_size,
                              hipStream_t stream)
{
    const float4* x     = (const float4*)d_in[0];
    const float*  w     = (const float*) d_in[1];
    const float*  gamma = (const float*) d_in[2];
    const float*  beta  = (const float*) d_in[3];
    const int*    nidx  = (const int*)   d_in[4];
    const int*    pidx  = (const int*)   d_in[5];
    const int*    depth = (const int*)   d_in[6];

    const int n_in   = in_sizes[0] / 4;
    const int n_out  = in_sizes[4] / KNB;
    const int n_pool = in_sizes[5] / 8;
    const int band   = (n_in + NBANDS - 1) / NBANDS;   // ~250k rows = 2MB

    // workspace layout
    float* stats      = (float*)d_ws;                       // 128 f32
    float* scaleshift = (float*)((char*)d_ws + 512);        // 128 f32
    unsigned short* yb = (unsigned short*)((char*)d_ws + 1024);  // n_out*64 bf16
    size_t yb_bytes   = ((size_t)n_out * COUT * 2 + 255) & ~(size_t)255;
    uint2* xb         = (uint2*)((char*)d_ws + 1024 + yb_bytes); // n_in*8 B
    float* out        = (float*)d_out;

    hipMemsetAsync(stats, 0, 2 * COUT * sizeof(float), stream);

    xconv_kernel<<<(n_in + 255) / 256, 256, 0, stream>>>(x, xb, n_in);

    // 8 blocks/CU co-resident (LDS 18.4KB x 8 = 147KB), single generation
    conv_stats_kernel<<<2048, 256, 0, stream>>>(xb, w, nidx, yb, stats,
                                                n_out, band);

    const int write_depth = (out_size > n_pool * COUT) ? 1 : 0;
    finalize_kernel<<<1, 64, 0, stream>>>(stats, gamma, beta, scaleshift,
                                          depth, out + (size_t)n_pool * COUT,
                                          n_out, write_depth);

    const int pool_blocks = (n_pool * 16 + 255) / 256;
    pool_kernel<<<pool_blocks, 256, 0, stream>>>((const uint2*)yb, pidx,
                                                 (const float4*)scaleshift,
                                                 (float4*)out, n_pool);
}

// Round 7
// 188.029 us; speedup vs baseline: 1.0047x; 1.0047x over previous
//
#include <hip/hip_runtime.h>

#define COUT 64
#define KNB 27
#define BN_EPS 1e-5f
#define NBANDS 6

typedef __attribute__((ext_vector_type(8))) short short8v;  // 8 bf16 (4 VGPRs)
typedef __attribute__((ext_vector_type(4))) float f32x4;

union U4S8 { uint4 u; short8v s; };

// f32 -> bf16, round-to-nearest-even
static __device__ __forceinline__ unsigned f2bf(float f) {
    unsigned u = __float_as_uint(f);
    return (u + 0x7fffu + ((u >> 16) & 1u)) >> 16;
}

// ---------------- Kernel 0: pre-convert x rows to packed bf16 ----------------
__global__ __launch_bounds__(256) void xconv_kernel(
    const float4* __restrict__ x, uint2* __restrict__ xb, int n_in)
{
    int i = blockIdx.x * 256 + threadIdx.x;
    if (i >= n_in) return;
    float4 r = x[i];
    uint2 o;
    o.x = f2bf(r.x) | (f2bf(r.y) << 16);
    o.y = f2bf(r.z) | (f2bf(r.w) << 16);
    xb[i] = o;
}

// ---------------- Kernel 1: banded MFMA gather-conv + BN stats ----------------
// Wave owns 16 nodes. R7 = R5's drain discipline (per-band vmcnt(0)+s_barrier,
// which provides BOTH temporal band locality in L2 and WAW-hazard clearance on
// the shared xa registers) + 8 blocks/CU co-residency: blocks don't share
// barriers, so other blocks issue while one block drains -> CU load pipe
// stays fed. R6 lesson: issue-order alone does NOT separate bands in time;
// the drain is load-bearing for locality.
__global__ __launch_bounds__(256, 8) void conv_stats_kernel(
    const uint2* __restrict__ xb,      // [N_in] packed bf16 rows (8B)
    const float* __restrict__ w,       // [27][4][64]
    const int*   __restrict__ nidx,    // [N_out][27]
    unsigned short* __restrict__ yb,   // [N_out][64] bf16 (workspace)
    float*       __restrict__ stats,   // [128]: sum[64], sumsq[64]
    int n_out, int band)
{
    const int lane = threadIdx.x & 63;
    const int wid  = threadIdx.x >> 6;
    const int row  = lane & 15;   // A-row (node) / B-col (channel) selector
    const int grp  = lane >> 4;   // k-chunk selector
    const int gwave   = blockIdx.x * 4 + wid;
    const int nwaves  = gridDim.x * 4;
    const int ngroups = (n_out + 15) >> 4;
    const int niter   = (ngroups + nwaves - 1) / nwaves;  // uniform trip count

    // ---- stage B fragments into LDS (16 frag-sets x 64 lanes x 16B = 16KB) ----
    __shared__ uint4 blds[16 * 64];
#pragma unroll
    for (int pp = 0; pp < 4; ++pp) {
        const int pair = wid * 4 + pp;        // pair = kb*4 + t
        const int kb = pair >> 2, t = pair & 3;
        const int o = t * 16 + row;
        unsigned e[8];
#pragma unroll
        for (int j = 0; j < 8; ++j) {
            const int k = kb * 32 + grp * 8 + j;
            float v = (k < KNB * 4) ? w[k * COUT + o] : 0.0f;
            e[j] = f2bf(v);
        }
        uint4 f;
        f.x = e[0] | (e[1] << 16);
        f.y = e[2] | (e[3] << 16);
        f.z = e[4] | (e[5] << 16);
        f.w = e[6] | (e[7] << 16);
        blds[pair * 64 + lane] = f;
    }
    __syncthreads();

    float sum[4]   = {0.f, 0.f, 0.f, 0.f};
    float sumsq[4] = {0.f, 0.f, 0.f, 0.f};

    auto load_ia = [&](int gg, int (&ia)[4][2]) {
        const int nodeg = (gg << 4) + row;
        const bool vn = (gg < ngroups) && (nodeg < n_out);
#pragma unroll
        for (int kb = 0; kb < 4; ++kb)
#pragma unroll
            for (int h = 0; h < 2; ++h) {
                const int nb = kb * 8 + grp * 2 + h;
                ia[kb][h] = (vn && nb < KNB) ? nidx[nodeg * KNB + nb] : -1;
            }
    };

    int ia_cur[4][2];
    load_ia(gwave, ia_cur);

    for (int it = 0; it < niter; ++it) {
        const int g = gwave + it * nwaves;   // may exceed ngroups (then ia=-1)

        uint2 xa[4][2];
#pragma unroll
        for (int kb = 0; kb < 4; ++kb)
#pragma unroll
            for (int h = 0; h < 2; ++h) xa[kb][h] = make_uint2(0u, 0u);

        int ia_nxt[4][2];

        // ---- banded gather sweep: per-band drain (R5 discipline) ----
#pragma unroll
        for (int b = 0; b < NBANDS; ++b) {
            const int lo = b * band;
#pragma unroll
            for (int kb = 0; kb < 4; ++kb)
#pragma unroll
                for (int h = 0; h < 2; ++h) {
                    if ((unsigned)(ia_cur[kb][h] - lo) < (unsigned)band)
                        xa[kb][h] = xb[ia_cur[kb][h]];   // exec-masked gather
                }
            if (b == 0) load_ia(g + nwaves, ia_nxt);  // prefetch during band 0
            __builtin_amdgcn_sched_barrier(0);
            asm volatile("s_waitcnt vmcnt(0)" ::: "memory");
            __builtin_amdgcn_s_barrier();
            __builtin_amdgcn_sched_barrier(0);
        }

        // ---- 16 MFMAs; A-frag = raw packed bits, B-frag from LDS ----
        f32x4 acc[4];
#pragma unroll
        for (int t = 0; t < 4; ++t) acc[t] = (f32x4){0.f, 0.f, 0.f, 0.f};
#pragma unroll
        for (int kb = 0; kb < 4; ++kb) {
            U4S8 a;
            a.u = make_uint4(xa[kb][0].x, xa[kb][0].y, xa[kb][1].x, xa[kb][1].y);
#pragma unroll
            for (int t = 0; t < 4; ++t) {
                U4S8 b;
                b.u = blds[(kb * 4 + t) * 64 + lane];
                acc[t] = __builtin_amdgcn_mfma_f32_16x16x32_bf16(
                             a.s, b.s, acc[t], 0, 0, 0);
            }
        }

        // ---- store y (bf16) + accumulate stats ----
        // C/D layout: channel = t*16 + (lane&15), node = gbase + grp*4 + j.
        const int gbase = g << 4;
#pragma unroll
        for (int t = 0; t < 4; ++t) {
#pragma unroll
            for (int j = 0; j < 4; ++j) {
                const int nr = gbase + grp * 4 + j;
                const float v = acc[t][j];
                if (nr < n_out)
                    yb[(size_t)nr * COUT + t * 16 + row] = (unsigned short)f2bf(v);
                sum[t]   += v;                 // padded rows contribute exact 0
                sumsq[t]  = fmaf(v, v, sumsq[t]);
            }
        }

#pragma unroll
        for (int kb = 0; kb < 4; ++kb)
#pragma unroll
            for (int h = 0; h < 2; ++h) ia_cur[kb][h] = ia_nxt[kb][h];
    }

    // Reduce stats: shfl over grp (16,32), 4-wave LDS reduce, 1 atomic/channel.
    __shared__ float redS[4][4][16];
    __shared__ float redQ[4][4][16];
#pragma unroll
    for (int t = 0; t < 4; ++t) {
        float s = sum[t], q = sumsq[t];
        s += __shfl_xor(s, 16); s += __shfl_xor(s, 32);
        q += __shfl_xor(q, 16); q += __shfl_xor(q, 32);
        if (lane < 16) { redS[wid][t][lane] = s; redQ[wid][t][lane] = q; }
    }
    __syncthreads();
    if (threadIdx.x < 128) {
        const int which = threadIdx.x >> 6;       // 0 = sum, 1 = sumsq
        const int o = threadIdx.x & 63;
        const int t = o >> 4, c = o & 15;
        float tot;
        if (which == 0)
            tot = redS[0][t][c] + redS[1][t][c] + redS[2][t][c] + redS[3][t][c];
        else
            tot = redQ[0][t][c] + redQ[1][t][c] + redQ[2][t][c] + redQ[3][t][c];
        atomicAdd(&stats[which * COUT + o], tot);
    }
}

// ---------------- Kernel 2: finalize BN affine + write depth output ----------------
__global__ void finalize_kernel(
    const float* __restrict__ stats,
    const float* __restrict__ gamma,
    const float* __restrict__ beta,
    float*       __restrict__ scaleshift,  // [128]: scale[64], shift[64]
    const int*   __restrict__ depth,
    float*       __restrict__ out_tail,    // &out[n_pool*64]
    int n_out, int write_depth)
{
    int o = threadIdx.x;
    if (o < COUT) {
        float invn  = 1.0f / (float)n_out;
        float mean  = stats[o] * invn;
        float var   = stats[COUT + o] * invn - mean * mean;  // population var
        float scale = gamma[o] * rsqrtf(var + BN_EPS);
        scaleshift[o]        = scale;
        scaleshift[COUT + o] = beta[o] - mean * scale;
    }
    if (o == 0 && write_depth) {
        out_tail[0] = (float)(depth[0] - 2);
    }
}

// ---------------- Kernel 3: affine + ReLU + max-pool over 8 children ----------------
__global__ __launch_bounds__(256) void pool_kernel(
    const uint2*  __restrict__ yb2,        // y as [N_out][16] packed bf16 quads
    const int*    __restrict__ pidx,       // [N_pool][8]
    const float4* __restrict__ scaleshift4,// [32]: scale4[16], shift4[16]
    float4*       __restrict__ out4,       // [N_pool][16]
    int n_pool)
{
    const int t = blockIdx.x * 256 + threadIdx.x;
    const int q = t & 15;
    const int n = t >> 4;
    if (n >= n_pool) return;

    const float4 sc = scaleshift4[q];
    const float4 sh = scaleshift4[16 + q];

    int idx[8];
#pragma unroll
    for (int j = 0; j < 8; ++j) idx[j] = pidx[n * 8 + j];

    uint2 v[8];
#pragma unroll
    for (int j = 0; j < 8; ++j) v[j] = yb2[(size_t)idx[j] * 16 + q];

    float4 m = make_float4(-INFINITY, -INFINITY, -INFINITY, -INFINITY);
#pragma unroll
    for (int j = 0; j < 8; ++j) {
        float f0 = __uint_as_float(v[j].x << 16);
        float f1 = __uint_as_float(v[j].x & 0xffff0000u);
        float f2 = __uint_as_float(v[j].y << 16);
        float f3 = __uint_as_float(v[j].y & 0xffff0000u);
        m.x = fmaxf(m.x, fmaf(f0, sc.x, sh.x));
        m.y = fmaxf(m.y, fmaf(f1, sc.y, sh.y));
        m.z = fmaxf(m.z, fmaf(f2, sc.z, sh.z));
        m.w = fmaxf(m.w, fmaf(f3, sc.w, sh.w));
    }
    m.x = fmaxf(m.x, 0.f); m.y = fmaxf(m.y, 0.f);
    m.z = fmaxf(m.z, 0.f); m.w = fmaxf(m.w, 0.f);
    out4[(size_t)n * 16 + q] = m;
}

// ---------------- Launch ----------------
extern "C" void kernel_launch(void* const* d_in, const int* in_sizes, int n_in_args,
                              void* d_out, int out_size, void* d_ws, size_t ws_size,
                              hipStream_t stream)
{
    const float4* x     = (const float4*)d_in[0];
    const float*  w     = (const float*) d_in[1];
    const float*  gamma = (const float*) d_in[2];
    const float*  beta  = (const float*) d_in[3];
    const int*    nidx  = (const int*)   d_in[4];
    const int*    pidx  = (const int*)   d_in[5];
    const int*    depth = (const int*)   d_in[6];

    const int n_in   = in_sizes[0] / 4;
    const int n_out  = in_sizes[4] / KNB;
    const int n_pool = in_sizes[5] / 8;
    const int band   = (n_in + NBANDS - 1) / NBANDS;   // ~250k rows = 2MB

    // workspace layout
    float* stats      = (float*)d_ws;                       // 128 f32
    float* scaleshift = (float*)((char*)d_ws + 512);        // 128 f32
    unsigned short* yb = (unsigned short*)((char*)d_ws + 1024);  // n_out*64 bf16
    size_t yb_bytes   = ((size_t)n_out * COUT * 2 + 255) & ~(size_t)255;
    uint2* xb         = (uint2*)((char*)d_ws + 1024 + yb_bytes); // n_in*8 B
    float* out        = (float*)d_out;

    hipMemsetAsync(stats, 0, 2 * COUT * sizeof(float), stream);

    xconv_kernel<<<(n_in + 255) / 256, 256, 0, stream>>>(x, xb, n_in);

    // 8 blocks/CU co-resident (LDS 18.4KB x 8 = 147KB), single generation;
    // per-block drains keep bands time-separated, other blocks hide the drain.
    conv_stats_kernel<<<2048, 256, 0, stream>>>(xb, w, nidx, yb, stats,
                                                n_out, band);

    const int write_depth = (out_size > n_pool * COUT) ? 1 : 0;
    finalize_kernel<<<1, 64, 0, stream>>>(stats, gamma, beta, scaleshift,
                                          depth, out + (size_t)n_pool * COUT,
                                          n_out, write_depth);

    const int pool_blocks = (n_pool * 16 + 255) / 256;
    pool_kernel<<<pool_blocks, 256, 0, stream>>>((const uint2*)yb, pidx,
                                                 (const float4*)scaleshift,
                                                 (float4*)out, n_pool);
}